// Round 3
// baseline (2185.090 us; speedup 1.0000x reference)
//
#include <hip/hip_runtime.h>
#include <math.h>

#define NFULL 1024
#define CDIM  512
#define HD    64
#define NH    8
#define TI    16

// ---------------- bucket ids ----------------
__device__ __forceinline__ int pwidx(int d) {
  int ad = d < 0 ? -d : d;
  if (ad <= 1) return d;                       // |d| <= 1.9, d integer
  float v = 1.9f + logf((float)ad * (1.0f / 1.9f)) * (1.9f / 2.0794415416798357f); // ln(8)
  v = fminf(v, 3.8f);
  int m = (int)rintf(v);                       // round-half-even, matches jnp.round
  if (m > 4) m = 4;
  return d > 0 ? m : -m;
}

__global__ __launch_bounds__(256) void bucket_kernel(int* __restrict__ bucket) {
  int idx = blockIdx.x * 256 + threadIdx.x;    // over N*N
  int i = idx >> 10, j = idx & 1023;
  int iy = i >> 5, ix = i & 31, jy = j >> 5, jx = j & 31;
  bucket[idx] = (pwidx(iy - jy) + 4) * 9 + (pwidx(ix - jx) + 4);
}

// ---------------- layernorm (one block per row of 512) ----------------
__global__ __launch_bounds__(256) void ln_kernel(const float* __restrict__ x,
                                                 const float* __restrict__ g,
                                                 const float* __restrict__ be,
                                                 float* __restrict__ y) {
  __shared__ float red[8];
  int row = blockIdx.x, tid = threadIdx.x;
  const float* xr = x + (size_t)row * CDIM;
  float v0 = xr[tid], v1 = xr[tid + 256];
  float s = v0 + v1;
#pragma unroll
  for (int off = 32; off; off >>= 1) s += __shfl_xor(s, off);
  int wid = tid >> 6, lane = tid & 63;
  if (!lane) red[wid] = s;
  __syncthreads();
  float mu = (red[0] + red[1] + red[2] + red[3]) * (1.0f / 512.0f);
  float d0 = v0 - mu, d1 = v1 - mu;
  float q = d0 * d0 + d1 * d1;
#pragma unroll
  for (int off = 32; off; off >>= 1) q += __shfl_xor(q, off);
  if (!lane) red[4 + wid] = q;
  __syncthreads();
  float var = (red[4] + red[5] + red[6] + red[7]) * (1.0f / 512.0f);
  float rstd = rsqrtf(var + 1e-5f);
  float* yr = y + (size_t)row * CDIM;
  yr[tid]       = d0 * rstd * g[tid]       + be[tid];
  yr[tid + 256] = d1 * rstd * g[tid + 256] + be[tid + 256];
}

// ---------------- generic fp32 GEMM: C = act(A@B + bias) (+res) ----------------
__device__ __forceinline__ float gelu_f(float x) {
  return 0.5f * x * (1.0f + erff(x * 0.7071067811865475f));
}

template <int RG, int CG, int ACT, int RES>
__global__ __launch_bounds__(256) void gemm_f32(const float* __restrict__ A,
                                                const float* __restrict__ Bm,
                                                const float* __restrict__ bias,
                                                const float* __restrict__ res,
                                                float* __restrict__ C,
                                                int M, int N, int K) {
  constexpr int BM = 64 * RG, BN = 64 * CG, BK = 32;
  __shared__ __attribute__((aligned(16))) float As[BK][BM + 4];  // transposed: As[k][m]
  __shared__ __attribute__((aligned(16))) float Bs[BK][BN + 4];
  const int tid = threadIdx.x;
  const int bm = blockIdx.y * BM, bn = blockIdx.x * BN;
  const int ty = tid >> 4, tx = tid & 15;
  float acc[4 * RG][4 * CG] = {};

  for (int k0 = 0; k0 < K; k0 += BK) {
    __syncthreads();
#pragma unroll
    for (int it = 0; it < RG * 2; ++it) {
      int e = tid + it * 256;
      int ar = e >> 3, ac = (e & 7) * 4;
      float4 av = *(const float4*)(A + (size_t)(bm + ar) * K + k0 + ac);
      As[ac + 0][ar] = av.x; As[ac + 1][ar] = av.y;
      As[ac + 2][ar] = av.z; As[ac + 3][ar] = av.w;
    }
#pragma unroll
    for (int it = 0; it < CG * 2; ++it) {
      int e = tid + it * 256;
      int br, bc;
      if (CG == 2) { br = e >> 5; bc = (e & 31) * 4; }
      else         { br = e >> 4; bc = (e & 15) * 4; }
      *(float4*)&Bs[br][bc] = *(const float4*)(Bm + (size_t)(k0 + br) * N + bn + bc);
    }
    __syncthreads();
#pragma unroll
    for (int kk = 0; kk < BK; ++kk) {
      float a[4 * RG], b[4 * CG];
#pragma unroll
      for (int rg = 0; rg < RG; ++rg)
        *(float4*)&a[rg * 4] = *(const float4*)&As[kk][(ty + 16 * rg) * 4];
#pragma unroll
      for (int cg = 0; cg < CG; ++cg)
        *(float4*)&b[cg * 4] = *(const float4*)&Bs[kk][(tx + 16 * cg) * 4];
#pragma unroll
      for (int i = 0; i < 4 * RG; ++i)
#pragma unroll
        for (int j = 0; j < 4 * CG; ++j)
          acc[i][j] = fmaf(a[i], b[j], acc[i][j]);
    }
  }
  // epilogue
  float bv[4 * CG];
#pragma unroll
  for (int cg = 0; cg < CG; ++cg)
    *(float4*)&bv[cg * 4] = *(const float4*)(bias + bn + (tx + 16 * cg) * 4);
#pragma unroll
  for (int rg = 0; rg < RG; ++rg) {
#pragma unroll
    for (int r = 0; r < 4; ++r) {
      int row = bm + (ty + 16 * rg) * 4 + r;
#pragma unroll
      for (int cg = 0; cg < CG; ++cg) {
        int col = bn + (tx + 16 * cg) * 4;
        float o[4];
#pragma unroll
        for (int c = 0; c < 4; ++c) {
          float v = acc[rg * 4 + r][cg * 4 + c] + bv[cg * 4 + c];
          if (ACT == 1) v = gelu_f(v);
          o[c] = v;
        }
        if (RES) {
          float rr[4];
          *(float4*)rr = *(const float4*)(res + (size_t)row * N + col);
#pragma unroll
          for (int c = 0; c < 4; ++c) o[c] += rr[c];
        }
        *(float4*)(C + (size_t)row * N + col) = *(float4*)o;
      }
    }
  }
}

// ---------------- table products: out[b,h,i,c] = scl * dot(X[b,i,h*64:+64], T[c,:]) ----------------
__global__ __launch_bounds__(256) void tableprod_kernel(const float* __restrict__ X, int ldx,
                                                        const float* __restrict__ T,
                                                        float* __restrict__ out, float scl) {
  __shared__ __attribute__((aligned(16))) float Ts[81 * 65];
  __shared__ __attribute__((aligned(16))) float xr[512];
  int r = blockIdx.x;  // b*N + i
  int tid = threadIdx.x;
  for (int f = tid; f < 81 * 64; f += 256) Ts[(f >> 6) * 65 + (f & 63)] = T[f];
  xr[tid]       = X[(size_t)r * ldx + tid];
  xr[tid + 256] = X[(size_t)r * ldx + tid + 256];
  __syncthreads();
  int b = r >> 10, i = r & 1023;
  for (int f = tid; f < NH * 81; f += 256) {
    int hh = f / 81, c = f - hh * 81;
    const float* xp = &xr[hh * 64];
    const float* tp = &Ts[c * 65];
    float dot = 0.f;
#pragma unroll
    for (int d = 0; d < 64; ++d) dot = fmaf(xp[d], tp[d], dot);
    out[((size_t)(b * NH + hh) * NFULL + i) * 81 + c] = dot * scl;
  }
}

// ---------------- fused attention (scores in registers) ----------------
// block = (b, h, 16 q-rows), 256 threads = 4 waves. Wave w owns rows 4w..4w+3.
// Lane l holds score s[r][tt] for j = l + 64*tt  (tt = 0..15).
// NOTE: all loops touching s[][] are fully unrolled — runtime indexing of a
// per-thread array demotes it to scratch (HBM!) on gfx950 (seen in round 2:
// WRITE_SIZE 535 MB/dispatch at VGPR=84).
__global__ __launch_bounds__(256, 2) void attn_kernel(const float* __restrict__ q,
                                                      const float* __restrict__ k,
                                                      const float* __restrict__ v,
                                                      int ld,
                                                      const float* __restrict__ lk,
                                                      const float* __restrict__ lq,
                                                      const int* __restrict__ bucket,
                                                      const float* __restrict__ tv,
                                                      float* __restrict__ o) {
  __shared__ __attribute__((aligned(16))) float kbuf[8192];      // 32 KB union buffer
  __shared__ __attribute__((aligned(16))) float qbuf[TI][HD];    // 4 KB
  __shared__ float lkb[TI][81];                                  // 5.2 KB
  __shared__ float wb[TI][81];                                   // 5.2 KB

  const int tid = threadIdx.x;
  const int i0 = blockIdx.x * TI;
  const int h = blockIdx.y;
  const int b = blockIdx.z;
  const int w = tid >> 6;       // wave id (0..3)
  const int l = tid & 63;       // lane
  const size_t bh = (size_t)(b * NH + h);

  // ---- prologue: q tile + lk rows + zero histogram ----
  {
    int r = tid >> 4, c4 = (tid & 15) * 4;
    *(float4*)&qbuf[r][c4] =
        *(const float4*)(q + ((size_t)b * NFULL + i0 + r) * ld + h * HD + c4);
    for (int f = tid; f < TI * 81; f += 256) {
      int rr = f / 81, c = f - rr * 81;
      lkb[rr][c] = lk[(bh * NFULL + i0 + rr) * 81 + c];
      wb[rr][c] = 0.f;
    }
  }

  float s[4][16];
#pragma unroll
  for (int r = 0; r < 4; ++r)
#pragma unroll
    for (int t = 0; t < 16; ++t) s[r][t] = 0.f;

  const int slotm = l & 15;

  // ---- phase 1: QK^T, k staged in 128-row LDS tiles ----
#pragma unroll
  for (int T = 0; T < 8; ++T) {
    __syncthreads();
#pragma unroll
    for (int it = 0; it < 8; ++it) {
      int e = tid + it * 256;
      int r = e >> 4, c4 = e & 15;
      int slot = c4 ^ (r & 15);
      *(float4*)&kbuf[r * 64 + slot * 4] =
          *(const float4*)(k + ((size_t)b * NFULL + T * 128 + r) * ld + h * HD + c4 * 4);
    }
    __syncthreads();
#pragma unroll
    for (int d4 = 0; d4 < 16; ++d4) {
      float k1[4], k2[4];
      *(float4*)k1 = *(const float4*)&kbuf[l * 64 + ((d4 ^ slotm) * 4)];
      *(float4*)k2 = *(const float4*)&kbuf[(l + 64) * 64 + ((d4 ^ slotm) * 4)];
#pragma unroll
      for (int r = 0; r < 4; ++r) {
        float qv[4];
        *(float4*)qv = *(const float4*)&qbuf[4 * w + r][d4 * 4];
#pragma unroll
        for (int u = 0; u < 4; ++u) {
          s[r][2 * T]     = fmaf(qv[u], k1[u], s[r][2 * T]);
          s[r][2 * T + 1] = fmaf(qv[u], k2[u], s[r][2 * T + 1]);
        }
      }
    }
  }

  // ---- phase 2: biases (lq staged per 64-row tile in kbuf), pack bucket ids ----
  unsigned bpack[4][4] = {{0u, 0u, 0u, 0u}, {0u, 0u, 0u, 0u},
                          {0u, 0u, 0u, 0u}, {0u, 0u, 0u, 0u}};
#pragma unroll
  for (int tt = 0; tt < 16; ++tt) {
    __syncthreads();
    {
      const float4* src = (const float4*)(lq + (bh * NFULL + tt * 64) * 81);
      float4* dst = (float4*)kbuf;
      for (int f = tid; f < 1296; f += 256) dst[f] = src[f];  // 64*81 floats
    }
    __syncthreads();
#pragma unroll
    for (int r = 0; r < 4; ++r) {
      int i = 4 * w + r;
      int bb = bucket[(size_t)(i0 + i) * NFULL + tt * 64 + l];
      bpack[r][tt >> 2] |= (unsigned)bb << ((tt & 3) * 8);
      s[r][tt] = s[r][tt] * 0.125f + lkb[i][bb] + kbuf[l * 81 + (80 - bb)];
    }
  }

  // ---- phase 3: softmax (unnormalized, regs) + bucket histogram ----
  float sum4[4];
#pragma unroll
  for (int r = 0; r < 4; ++r) {
    int i = 4 * w + r;
    float m = -3.4e38f;
#pragma unroll
    for (int t = 0; t < 16; ++t) m = fmaxf(m, s[r][t]);
#pragma unroll
    for (int off = 32; off; off >>= 1) m = fmaxf(m, __shfl_xor(m, off));
    float psum = 0.f;
#pragma unroll
    for (int t = 0; t < 16; ++t) {
      int bb = (int)((bpack[r][t >> 2] >> ((t & 3) * 8)) & 0xffu);
      float p = __expf(s[r][t] - m);
      s[r][t] = p;
      psum += p;
      atomicAdd(&wb[i][bb], p);
    }
#pragma unroll
    for (int off = 32; off; off >>= 1) psum += __shfl_xor(psum, off);
    sum4[r] = psum;
  }

  // ---- phase 4: PV over 64-row v tiles; p through LDS ----
  // thread -> (rq = wave, dg = (tid>>3)&7 : 8 floats of d, js = tid&7 : 8 j's)
  const int dg = (tid >> 3) & 7;
  const int js = tid & 7;
  float* vbuf = kbuf;            // [64][64] swizzled, 16 KB
  float* pbuf = kbuf + 4096;     // [16][64], 4 KB
  float acc[4][8];
#pragma unroll
  for (int r = 0; r < 4; ++r)
#pragma unroll
    for (int c = 0; c < 8; ++c) acc[r][c] = 0.f;

#pragma unroll
  for (int T = 0; T < 16; ++T) {
    __syncthreads();
#pragma unroll
    for (int it = 0; it < 4; ++it) {
      int e = tid + it * 256;
      int r = e >> 4, c4 = e & 15;
      int slot = (c4 >> 1) ^ (r & 7);
      *(float4*)&vbuf[r * 64 + slot * 8 + (c4 & 1) * 4] =
          *(const float4*)(v + ((size_t)b * NFULL + T * 64 + r) * ld + h * HD + c4 * 4);
    }
#pragma unroll
    for (int r = 0; r < 4; ++r) pbuf[(4 * w + r) * 64 + l] = s[r][T];
    __syncthreads();
#pragma unroll
    for (int jj = 0; jj < 8; ++jj) {
      int j = js * 8 + jj;
      int slot = dg ^ jj;                   // j & 7 == jj
      float v0[4], v1[4];
      *(float4*)v0 = *(const float4*)&vbuf[j * 64 + slot * 8];
      *(float4*)v1 = *(const float4*)&vbuf[j * 64 + slot * 8 + 4];
#pragma unroll
      for (int r = 0; r < 4; ++r) {
        float p = pbuf[(4 * w + r) * 64 + j];
#pragma unroll
        for (int c = 0; c < 4; ++c) {
          acc[r][c]     = fmaf(p, v0[c], acc[r][c]);
          acc[r][4 + c] = fmaf(p, v1[c], acc[r][4 + c]);
        }
      }
    }
  }

  // ---- phase 5: tv-bucket term (parallel over js), reduce, normalize, store ----
#pragma unroll
  for (int cc = 0; cc <= 10; ++cc) {
    int c = cc * 8 + js;
    if (c < 81) {
      float t0[4], t1[4];
      *(float4*)t0 = *(const float4*)(tv + c * HD + dg * 8);
      *(float4*)t1 = *(const float4*)(tv + c * HD + dg * 8 + 4);
#pragma unroll
      for (int r = 0; r < 4; ++r) {
        float wv = wb[4 * w + r][c];
#pragma unroll
        for (int u = 0; u < 4; ++u) {
          acc[r][u]     = fmaf(wv, t0[u], acc[r][u]);
          acc[r][4 + u] = fmaf(wv, t1[u], acc[r][4 + u]);
        }
      }
    }
  }
#pragma unroll
  for (int off = 1; off <= 4; off <<= 1)
#pragma unroll
    for (int r = 0; r < 4; ++r)
#pragma unroll
      for (int c = 0; c < 8; ++c) acc[r][c] += __shfl_xor(acc[r][c], off);

  if (js == 0) {
#pragma unroll
    for (int r = 0; r < 4; ++r) {
      float rn = 1.0f / sum4[r];
      float o0[4], o1[4];
#pragma unroll
      for (int u = 0; u < 4; ++u) { o0[u] = acc[r][u] * rn; o1[u] = acc[r][4 + u] * rn; }
      float* op = o + ((size_t)b * NFULL + i0 + 4 * w + r) * CDIM + h * HD + dg * 8;
      *(float4*)op       = *(float4*)o0;
      *(float4*)(op + 4) = *(float4*)o1;
    }
  }
}

// ---------------- launch ----------------
extern "C" void kernel_launch(void* const* d_in, const int* in_sizes, int n_in,
                              void* d_out, int out_size, void* d_ws, size_t ws_size,
                              hipStream_t stream) {
  (void)in_sizes; (void)n_in; (void)out_size; (void)ws_size;
  const float* x0 = (const float*)d_in[0];
  const float* x1 = (const float*)d_in[1];
  const float* ln00_g = (const float*)d_in[2];
  const float* ln00_b = (const float*)d_in[3];
  const float* ln01_g = (const float*)d_in[4];
  const float* ln01_b = (const float*)d_in[5];
  const float* ln10_g = (const float*)d_in[6];
  const float* ln10_b = (const float*)d_in[7];
  const float* ln11_g = (const float*)d_in[8];
  const float* ln11_b = (const float*)d_in[9];
  const float* w_qkv0 = (const float*)d_in[10];
  const float* b_qkv0 = (const float*)d_in[11];
  const float* w_qkv1 = (const float*)d_in[12];
  const float* b_qkv1 = (const float*)d_in[13];
  const float* w_proj = (const float*)d_in[14];
  const float* b_proj = (const float*)d_in[15];
  const float* table_q = (const float*)d_in[16];
  const float* table_k = (const float*)d_in[17];
  const float* table_v = (const float*)d_in[18];
  const float* w_fc1_0 = (const float*)d_in[19];
  const float* b_fc1_0 = (const float*)d_in[20];
  const float* w_fc2_0 = (const float*)d_in[21];
  const float* b_fc2_0 = (const float*)d_in[22];
  const float* w_fc1_1 = (const float*)d_in[23];
  const float* b_fc1_1 = (const float*)d_in[24];
  const float* w_fc2_1 = (const float*)d_in[25];
  const float* b_fc2_1 = (const float*)d_in[26];

  char* base = (char*)d_ws;
  int*   bucket = (int*)base;                                   // 4 MB
  float* xn     = (float*)(base + 4194304);                     // 8 MB
  float* qkv0   = (float*)(base + 4194304 + 8388608);           // 24 MB
  float* qkv1   = qkv0 + (size_t)4 * 1024 * 1536;               // 24 MB
  float* lkbuf  = qkv1 + (size_t)4 * 1024 * 1536;               // 10.6 MB
  float* lqbuf  = lkbuf + (size_t)4 * 8 * 1024 * 81;            // 10.6 MB
  float* obuf   = lqbuf + (size_t)4 * 8 * 1024 * 81;            // 8 MB
  float* hbuf   = qkv0;  // alias: MLP hidden (32MB) reuses dead qkv region (48MB)
  float* dout0  = (float*)d_out;
  float* dout1  = dout0 + (size_t)4 * 1024 * 512;

  const int M = 4096;

  bucket_kernel<<<4096, 256, 0, stream>>>(bucket);

  ln_kernel<<<M, 256, 0, stream>>>(x0, ln00_g, ln00_b, xn);
  gemm_f32<2, 2, 0, 0><<<dim3(12, 32), 256, 0, stream>>>(xn, w_qkv0, b_qkv0, nullptr, qkv0, M, 1536, 512);
  ln_kernel<<<M, 256, 0, stream>>>(x1, ln01_g, ln01_b, xn);
  gemm_f32<2, 2, 0, 0><<<dim3(12, 32), 256, 0, stream>>>(xn, w_qkv1, b_qkv1, nullptr, qkv1, M, 1536, 512);

  // attention 0: q0 with k1/v1
  tableprod_kernel<<<M, 256, 0, stream>>>(qkv0, 1536, table_k, lkbuf, 1.0f);
  tableprod_kernel<<<M, 256, 0, stream>>>(qkv1 + 512, 1536, table_q, lqbuf, 0.125f);
  attn_kernel<<<dim3(64, 8, 4), 256, 0, stream>>>(qkv0, qkv1 + 512, qkv1 + 1024, 1536,
                                                  lkbuf, lqbuf, bucket, table_v, obuf);
  gemm_f32<2, 1, 0, 1><<<dim3(8, 32), 256, 0, stream>>>(obuf, w_proj, b_proj, x0, dout0, M, 512, 512);

  // attention 1: q1 with k0/v0
  tableprod_kernel<<<M, 256, 0, stream>>>(qkv1, 1536, table_k, lkbuf, 1.0f);
  tableprod_kernel<<<M, 256, 0, stream>>>(qkv0 + 512, 1536, table_q, lqbuf, 0.125f);
  attn_kernel<<<dim3(64, 8, 4), 256, 0, stream>>>(qkv1, qkv0 + 512, qkv0 + 1024, 1536,
                                                  lkbuf, lqbuf, bucket, table_v, obuf);
  gemm_f32<2, 1, 0, 1><<<dim3(8, 32), 256, 0, stream>>>(obuf, w_proj, b_proj, x1, dout1, M, 512, 512);

  // MLP 0
  ln_kernel<<<M, 256, 0, stream>>>(dout0, ln10_g, ln10_b, xn);
  gemm_f32<2, 2, 1, 0><<<dim3(16, 32), 256, 0, stream>>>(xn, w_fc1_0, b_fc1_0, nullptr, hbuf, M, 2048, 512);
  gemm_f32<2, 1, 0, 1><<<dim3(8, 32), 256, 0, stream>>>(hbuf, w_fc2_0, b_fc2_0, dout0, dout0, M, 512, 2048);

  // MLP 1
  ln_kernel<<<M, 256, 0, stream>>>(dout1, ln11_g, ln11_b, xn);
  gemm_f32<2, 2, 1, 0><<<dim3(16, 32), 256, 0, stream>>>(xn, w_fc1_1, b_fc1_1, nullptr, hbuf, M, 2048, 512);
  gemm_f32<2, 1, 0, 1><<<dim3(8, 32), 256, 0, stream>>>(hbuf, w_fc2_1, b_fc2_1, dout1, dout1, M, 512, 2048);
}

// Round 4
// 2102.257 us; speedup vs baseline: 1.0394x; 1.0394x over previous
//
#include <hip/hip_runtime.h>
#include <hip/hip_bf16.h>
#include <math.h>

#define NFULL 1024
#define CDIM  512
#define HD    64
#define NH    8
#define TI    16

typedef __attribute__((ext_vector_type(8))) short short8;
typedef __attribute__((ext_vector_type(4))) float f32x4;

// ---------------- bucket ids ----------------
__device__ __forceinline__ int pwidx(int d) {
  int ad = d < 0 ? -d : d;
  if (ad <= 1) return d;                       // |d| <= 1.9, d integer
  float v = 1.9f + logf((float)ad * (1.0f / 1.9f)) * (1.9f / 2.0794415416798357f); // ln(8)
  v = fminf(v, 3.8f);
  int m = (int)rintf(v);                       // round-half-even, matches jnp.round
  if (m > 4) m = 4;
  return d > 0 ? m : -m;
}

__global__ __launch_bounds__(256) void bucket_kernel(int* __restrict__ bucket) {
  int idx = blockIdx.x * 256 + threadIdx.x;    // over N*N
  int i = idx >> 10, j = idx & 1023;
  int iy = i >> 5, ix = i & 31, jy = j >> 5, jx = j & 31;
  bucket[idx] = (pwidx(iy - jy) + 4) * 9 + (pwidx(ix - jx) + 4);
}

// ---------------- layernorm (one block per row of 512), bf16 output ----------------
__global__ __launch_bounds__(256) void ln_kernel(const float* __restrict__ x,
                                                 const float* __restrict__ g,
                                                 const float* __restrict__ be,
                                                 __hip_bfloat16* __restrict__ y) {
  __shared__ float red[8];
  int row = blockIdx.x, tid = threadIdx.x;
  const float* xr = x + (size_t)row * CDIM;
  float v0 = xr[tid], v1 = xr[tid + 256];
  float s = v0 + v1;
#pragma unroll
  for (int off = 32; off; off >>= 1) s += __shfl_xor(s, off);
  int wid = tid >> 6, lane = tid & 63;
  if (!lane) red[wid] = s;
  __syncthreads();
  float mu = (red[0] + red[1] + red[2] + red[3]) * (1.0f / 512.0f);
  float d0 = v0 - mu, d1 = v1 - mu;
  float q = d0 * d0 + d1 * d1;
#pragma unroll
  for (int off = 32; off; off >>= 1) q += __shfl_xor(q, off);
  if (!lane) red[4 + wid] = q;
  __syncthreads();
  float var = (red[4] + red[5] + red[6] + red[7]) * (1.0f / 512.0f);
  float rstd = rsqrtf(var + 1e-5f);
  __hip_bfloat16* yr = y + (size_t)row * CDIM;
  yr[tid]       = __float2bfloat16(d0 * rstd * g[tid]       + be[tid]);
  yr[tid + 256] = __float2bfloat16(d1 * rstd * g[tid + 256] + be[tid + 256]);
}

// ---------------- weight transpose + bf16 cast: Wt[n][k] = bf16(W[k][n]) ----------------
__global__ __launch_bounds__(256) void wtrans_kernel(const float* __restrict__ W,
                                                     __hip_bfloat16* __restrict__ Wt,
                                                     int K, int N) {
  __shared__ float t[32][33];
  int n0 = blockIdx.x * 32, k0 = blockIdx.y * 32;
  int c = threadIdx.x, r0 = threadIdx.y;
#pragma unroll
  for (int rr = 0; rr < 32; rr += 8) t[r0 + rr][c] = W[(size_t)(k0 + r0 + rr) * N + n0 + c];
  __syncthreads();
#pragma unroll
  for (int rr = 0; rr < 32; rr += 8)
    Wt[(size_t)(n0 + r0 + rr) * K + k0 + c] = __float2bfloat16(t[c][r0 + rr]);
}

__device__ __forceinline__ float gelu_f(float x) {
  return 0.5f * x * (1.0f + erff(x * 0.7071067811865475f));
}

// ---------------- bf16 MFMA GEMM: C = act(A@B + bias) (+res) ----------------
// A: [M][K] bf16 row-major (K-major). Bt: [N][K] bf16 (transposed weights).
// 128x128 tile, BK=32, 4 waves in 2x2, each wave 64x64 via 4x4 mfma 16x16x32.
// LDS rows padded to 40 elems (80B): frag reads land 2 lanes/bank (free).
template <int ACT, int RES, int OUTBF>
__global__ __launch_bounds__(256, 1) void gemm_bf16(const short* __restrict__ A,
                                                    const short* __restrict__ Bt,
                                                    const float* __restrict__ bias,
                                                    const float* __restrict__ res,
                                                    void* __restrict__ Cout,
                                                    int M, int N, int K) {
  __shared__ __attribute__((aligned(16))) short As[128 * 40];
  __shared__ __attribute__((aligned(16))) short Bs[128 * 40];
  const int tid = threadIdx.x;
  const int bm = blockIdx.y * 128, bn = blockIdx.x * 128;
  const int w = tid >> 6, l = tid & 63;
  const int wr = w >> 1, wc = w & 1;
  const int lr = l & 15, lg = l >> 4;
  const int sr = tid >> 1, sh = (tid & 1) * 16;   // staging: row, 16-elem half

  f32x4 acc[4][4] = {};

  for (int k0 = 0; k0 < K; k0 += 32) {
    __syncthreads();
    const float4* ga = (const float4*)(A + (size_t)(bm + sr) * K + k0 + sh);
    const float4* gb = (const float4*)(Bt + (size_t)(bn + sr) * K + k0 + sh);
    float4 a0 = ga[0], a1 = ga[1];
    float4 b0 = gb[0], b1 = gb[1];
    *(float4*)&As[sr * 40 + sh]     = a0;
    *(float4*)&As[sr * 40 + sh + 8] = a1;
    *(float4*)&Bs[sr * 40 + sh]     = b0;
    *(float4*)&Bs[sr * 40 + sh + 8] = b1;
    __syncthreads();
    short8 af[4], bf[4];
#pragma unroll
    for (int mi = 0; mi < 4; ++mi)
      af[mi] = *(const short8*)&As[(wr * 64 + mi * 16 + lr) * 40 + lg * 8];
#pragma unroll
    for (int ni = 0; ni < 4; ++ni)
      bf[ni] = *(const short8*)&Bs[(wc * 64 + ni * 16 + lr) * 40 + lg * 8];
#pragma unroll
    for (int mi = 0; mi < 4; ++mi)
#pragma unroll
      for (int ni = 0; ni < 4; ++ni)
        acc[mi][ni] = __builtin_amdgcn_mfma_f32_16x16x32_bf16(af[mi], bf[ni], acc[mi][ni], 0, 0, 0);
  }

  // epilogue: C[row][col], col = lane&15, row = (lane>>4)*4 + reg  (m89 layout)
  float bv[4];
#pragma unroll
  for (int ni = 0; ni < 4; ++ni) bv[ni] = bias[bn + wc * 64 + ni * 16 + lr];
#pragma unroll
  for (int mi = 0; mi < 4; ++mi) {
#pragma unroll
    for (int j = 0; j < 4; ++j) {
      int row = bm + wr * 64 + mi * 16 + lg * 4 + j;
#pragma unroll
      for (int ni = 0; ni < 4; ++ni) {
        int col = bn + wc * 64 + ni * 16 + lr;
        float vv = acc[mi][ni][j] + bv[ni];
        if (ACT) vv = gelu_f(vv);
        if (RES) vv += res[(size_t)row * N + col];
        if (OUTBF) ((__hip_bfloat16*)Cout)[(size_t)row * N + col] = __float2bfloat16(vv);
        else       ((float*)Cout)[(size_t)row * N + col] = vv;
      }
    }
  }
}

// ---------------- table products: out[b,h,i,c] = scl * dot(X[b,i,h*64:+64], T[c,:]) ----------------
__global__ __launch_bounds__(256) void tableprod_kernel(const float* __restrict__ X, int ldx,
                                                        const float* __restrict__ T,
                                                        float* __restrict__ out, float scl) {
  __shared__ __attribute__((aligned(16))) float Ts[81 * 65];
  __shared__ __attribute__((aligned(16))) float xr[512];
  int r = blockIdx.x;  // b*N + i
  int tid = threadIdx.x;
  for (int f = tid; f < 81 * 64; f += 256) Ts[(f >> 6) * 65 + (f & 63)] = T[f];
  xr[tid]       = X[(size_t)r * ldx + tid];
  xr[tid + 256] = X[(size_t)r * ldx + tid + 256];
  __syncthreads();
  int b = r >> 10, i = r & 1023;
  for (int f = tid; f < NH * 81; f += 256) {
    int hh = f / 81, c = f - hh * 81;
    const float* xp = &xr[hh * 64];
    const float* tp = &Ts[c * 65];
    float dot = 0.f;
#pragma unroll
    for (int d = 0; d < 64; ++d) dot = fmaf(xp[d], tp[d], dot);
    out[((size_t)(b * NH + hh) * NFULL + i) * 81 + c] = dot * scl;
  }
}

// ---------------- fused attention (scores in registers), bf16 output ----------------
// block = (b, h, 16 q-rows), 256 threads = 4 waves. Wave w owns rows 4w..4w+3.
// Lane l holds score s[r][tt] for j = l + 64*tt  (tt = 0..15).
// All loops touching s[][] fully unrolled (rule #20: runtime indexing -> scratch).
// launch_bounds(256,1): compiler VGPR budget scales as ~256/min_waves; at (256,2)
// it capped 128 and spilled ~86 floats/thread (round 3: WRITE_SIZE 188MB).
__global__ __launch_bounds__(256, 1) void attn_kernel(const float* __restrict__ q,
                                                      const float* __restrict__ k,
                                                      const float* __restrict__ v,
                                                      int ld,
                                                      const float* __restrict__ lk,
                                                      const float* __restrict__ lq,
                                                      const int* __restrict__ bucket,
                                                      const float* __restrict__ tv,
                                                      __hip_bfloat16* __restrict__ o) {
  __shared__ __attribute__((aligned(16))) float kbuf[8192];      // 32 KB union buffer
  __shared__ __attribute__((aligned(16))) float qbuf[TI][HD];    // 4 KB
  __shared__ float lkb[TI][81];                                  // 5.2 KB
  __shared__ float wb[TI][81];                                   // 5.2 KB

  const int tid = threadIdx.x;
  const int i0 = blockIdx.x * TI;
  const int h = blockIdx.y;
  const int b = blockIdx.z;
  const int w = tid >> 6;       // wave id (0..3)
  const int l = tid & 63;       // lane
  const size_t bh = (size_t)(b * NH + h);

  // ---- prologue: q tile + lk rows + zero histogram ----
  {
    int r = tid >> 4, c4 = (tid & 15) * 4;
    *(float4*)&qbuf[r][c4] =
        *(const float4*)(q + ((size_t)b * NFULL + i0 + r) * ld + h * HD + c4);
    for (int f = tid; f < TI * 81; f += 256) {
      int rr = f / 81, c = f - rr * 81;
      lkb[rr][c] = lk[(bh * NFULL + i0 + rr) * 81 + c];
      wb[rr][c] = 0.f;
    }
  }

  float s[4][16];
#pragma unroll
  for (int r = 0; r < 4; ++r)
#pragma unroll
    for (int t = 0; t < 16; ++t) s[r][t] = 0.f;

  const int slotm = l & 15;

  // ---- phase 1: QK^T, k staged in 128-row LDS tiles ----
#pragma unroll
  for (int T = 0; T < 8; ++T) {
    __syncthreads();
#pragma unroll
    for (int it = 0; it < 8; ++it) {
      int e = tid + it * 256;
      int r = e >> 4, c4 = e & 15;
      int slot = c4 ^ (r & 15);
      *(float4*)&kbuf[r * 64 + slot * 4] =
          *(const float4*)(k + ((size_t)b * NFULL + T * 128 + r) * ld + h * HD + c4 * 4);
    }
    __syncthreads();
#pragma unroll
    for (int d4 = 0; d4 < 16; ++d4) {
      float k1[4], k2[4];
      *(float4*)k1 = *(const float4*)&kbuf[l * 64 + ((d4 ^ slotm) * 4)];
      *(float4*)k2 = *(const float4*)&kbuf[(l + 64) * 64 + ((d4 ^ slotm) * 4)];
#pragma unroll
      for (int r = 0; r < 4; ++r) {
        float qv[4];
        *(float4*)qv = *(const float4*)&qbuf[4 * w + r][d4 * 4];
#pragma unroll
        for (int u = 0; u < 4; ++u) {
          s[r][2 * T]     = fmaf(qv[u], k1[u], s[r][2 * T]);
          s[r][2 * T + 1] = fmaf(qv[u], k2[u], s[r][2 * T + 1]);
        }
      }
    }
  }

  // ---- phase 2: biases (lq staged per 64-row tile in kbuf), pack bucket ids ----
  unsigned bpack[4][4] = {{0u, 0u, 0u, 0u}, {0u, 0u, 0u, 0u},
                          {0u, 0u, 0u, 0u}, {0u, 0u, 0u, 0u}};
#pragma unroll
  for (int tt = 0; tt < 16; ++tt) {
    __syncthreads();
    {
      const float4* src = (const float4*)(lq + (bh * NFULL + tt * 64) * 81);
      float4* dst = (float4*)kbuf;
      for (int f = tid; f < 1296; f += 256) dst[f] = src[f];  // 64*81 floats
    }
    __syncthreads();
#pragma unroll
    for (int r = 0; r < 4; ++r) {
      int i = 4 * w + r;
      int bb = bucket[(size_t)(i0 + i) * NFULL + tt * 64 + l];
      bpack[r][tt >> 2] |= (unsigned)bb << ((tt & 3) * 8);
      s[r][tt] = s[r][tt] * 0.125f + lkb[i][bb] + kbuf[l * 81 + (80 - bb)];
    }
  }

  // ---- phase 3: softmax (unnormalized, regs) + bucket histogram ----
  float sum4[4];
#pragma unroll
  for (int r = 0; r < 4; ++r) {
    int i = 4 * w + r;
    float m = -3.4e38f;
#pragma unroll
    for (int t = 0; t < 16; ++t) m = fmaxf(m, s[r][t]);
#pragma unroll
    for (int off = 32; off; off >>= 1) m = fmaxf(m, __shfl_xor(m, off));
    float psum = 0.f;
#pragma unroll
    for (int t = 0; t < 16; ++t) {
      int bb = (int)((bpack[r][t >> 2] >> ((t & 3) * 8)) & 0xffu);
      float p = __expf(s[r][t] - m);
      s[r][t] = p;
      psum += p;
      atomicAdd(&wb[i][bb], p);
    }
#pragma unroll
    for (int off = 32; off; off >>= 1) psum += __shfl_xor(psum, off);
    sum4[r] = psum;
  }

  // ---- phase 4: PV over 64-row v tiles; p through LDS ----
  const int dg = (tid >> 3) & 7;
  const int js = tid & 7;
  float* vbuf = kbuf;            // [64][64] swizzled, 16 KB
  float* pbuf = kbuf + 4096;     // [16][64], 4 KB
  float acc[4][8];
#pragma unroll
  for (int r = 0; r < 4; ++r)
#pragma unroll
    for (int c = 0; c < 8; ++c) acc[r][c] = 0.f;

#pragma unroll
  for (int T = 0; T < 16; ++T) {
    __syncthreads();
#pragma unroll
    for (int it = 0; it < 4; ++it) {
      int e = tid + it * 256;
      int r = e >> 4, c4 = e & 15;
      int slot = (c4 >> 1) ^ (r & 7);
      *(float4*)&vbuf[r * 64 + slot * 8 + (c4 & 1) * 4] =
          *(const float4*)(v + ((size_t)b * NFULL + T * 64 + r) * ld + h * HD + c4 * 4);
    }
#pragma unroll
    for (int r = 0; r < 4; ++r) pbuf[(4 * w + r) * 64 + l] = s[r][T];
    __syncthreads();
#pragma unroll
    for (int jj = 0; jj < 8; ++jj) {
      int j = js * 8 + jj;
      int slot = dg ^ jj;                   // j & 7 == jj
      float v0[4], v1[4];
      *(float4*)v0 = *(const float4*)&vbuf[j * 64 + slot * 8];
      *(float4*)v1 = *(const float4*)&vbuf[j * 64 + slot * 8 + 4];
#pragma unroll
      for (int r = 0; r < 4; ++r) {
        float p = pbuf[(4 * w + r) * 64 + j];
#pragma unroll
        for (int c = 0; c < 4; ++c) {
          acc[r][c]     = fmaf(p, v0[c], acc[r][c]);
          acc[r][4 + c] = fmaf(p, v1[c], acc[r][4 + c]);
        }
      }
    }
  }

  // ---- phase 5: tv-bucket term (parallel over js), reduce, normalize, store bf16 ----
#pragma unroll
  for (int cc = 0; cc <= 10; ++cc) {
    int c = cc * 8 + js;
    if (c < 81) {
      float t0[4], t1[4];
      *(float4*)t0 = *(const float4*)(tv + c * HD + dg * 8);
      *(float4*)t1 = *(const float4*)(tv + c * HD + dg * 8 + 4);
#pragma unroll
      for (int r = 0; r < 4; ++r) {
        float wv = wb[4 * w + r][c];
#pragma unroll
        for (int u = 0; u < 4; ++u) {
          acc[r][u]     = fmaf(wv, t0[u], acc[r][u]);
          acc[r][4 + u] = fmaf(wv, t1[u], acc[r][4 + u]);
        }
      }
    }
  }
#pragma unroll
  for (int off = 1; off <= 4; off <<= 1)
#pragma unroll
    for (int r = 0; r < 4; ++r)
#pragma unroll
      for (int c = 0; c < 8; ++c) acc[r][c] += __shfl_xor(acc[r][c], off);

  if (js == 0) {
#pragma unroll
    for (int r = 0; r < 4; ++r) {
      float rn = 1.0f / sum4[r];
      __hip_bfloat16 ob[8];
#pragma unroll
      for (int u = 0; u < 4; ++u) {
        ob[u]     = __float2bfloat16(acc[r][u] * rn);
        ob[4 + u] = __float2bfloat16(acc[r][4 + u] * rn);
      }
      __hip_bfloat16* op = o + ((size_t)b * NFULL + i0 + 4 * w + r) * CDIM + h * HD + dg * 8;
      *(float4*)op = *(float4*)ob;
    }
  }
}

// ---------------- launch ----------------
extern "C" void kernel_launch(void* const* d_in, const int* in_sizes, int n_in,
                              void* d_out, int out_size, void* d_ws, size_t ws_size,
                              hipStream_t stream) {
  (void)in_sizes; (void)n_in; (void)out_size; (void)ws_size;
  const float* x0 = (const float*)d_in[0];
  const float* x1 = (const float*)d_in[1];
  const float* ln00_g = (const float*)d_in[2];
  const float* ln00_b = (const float*)d_in[3];
  const float* ln01_g = (const float*)d_in[4];
  const float* ln01_b = (const float*)d_in[5];
  const float* ln10_g = (const float*)d_in[6];
  const float* ln10_b = (const float*)d_in[7];
  const float* ln11_g = (const float*)d_in[8];
  const float* ln11_b = (const float*)d_in[9];
  const float* w_qkv0 = (const float*)d_in[10];
  const float* b_qkv0 = (const float*)d_in[11];
  const float* w_qkv1 = (const float*)d_in[12];
  const float* b_qkv1 = (const float*)d_in[13];
  const float* w_proj = (const float*)d_in[14];
  const float* b_proj = (const float*)d_in[15];
  const float* table_q = (const float*)d_in[16];
  const float* table_k = (const float*)d_in[17];
  const float* table_v = (const float*)d_in[18];
  const float* w_fc1_0 = (const float*)d_in[19];
  const float* b_fc1_0 = (const float*)d_in[20];
  const float* w_fc2_0 = (const float*)d_in[21];
  const float* b_fc2_0 = (const float*)d_in[22];
  const float* w_fc1_1 = (const float*)d_in[23];
  const float* b_fc1_1 = (const float*)d_in[24];
  const float* w_fc2_1 = (const float*)d_in[25];
  const float* b_fc2_1 = (const float*)d_in[26];

  char* base = (char*)d_ws;
  int*   bucket = (int*)base;                                        // @0, 4MB
  __hip_bfloat16* xnb  = (__hip_bfloat16*)(base + 4194304);          // 4MB
  float* qkv0   = (float*)(base + 8388608);                          // 24MB
  float* qkv1   = (float*)(base + 33554432);                         // 24MB
  float* lkbuf  = (float*)(base + 58720256);                         // 10.6MB
  float* lqbuf  = (float*)(base + 69337088);                         // 10.6MB
  __hip_bfloat16* obuf = (__hip_bfloat16*)(base + 79953920);         // 4MB
  // qkv weight transposes alias obuf (dead before attn0 writes obuf)
  __hip_bfloat16* wq0t  = (__hip_bfloat16*)(base + 79953920);        // 1.5MB
  __hip_bfloat16* wq1t  = (__hip_bfloat16*)(base + 81526784);        // 1.5MB  <- WRONG if obuf live... see note
  __hip_bfloat16* wpt   = (__hip_bfloat16*)(base + 84148224);        // 0.5MB
  __hip_bfloat16* wf10t = (__hip_bfloat16*)(base + 84672512);        // 2MB
  __hip_bfloat16* wf20t = (__hip_bfloat16*)(base + 86769664);        // 2MB
  __hip_bfloat16* wf11t = (__hip_bfloat16*)(base + 88866816);        // 2MB
  __hip_bfloat16* wf21t = (__hip_bfloat16*)(base + 90963968);        // 2MB -> end 93.1MB
  __hip_bfloat16* hbufb = (__hip_bfloat16*)qkv0;  // MLP hidden bf16 16MB aliases dead qkv0
  float* dout0  = (float*)d_out;
  float* dout1  = dout0 + (size_t)4 * 1024 * 512;

  const int M = 4096;

  // NOTE on aliasing: wq0t/wq1t occupy the obuf region. They are consumed by the
  // qkv GEMMs, which complete before attn_kernel writes obuf. Sequential stream.

  bucket_kernel<<<4096, 256, 0, stream>>>(bucket);

  // weight transposes (fp32 -> bf16, [K][N] -> [N][K])
  wtrans_kernel<<<dim3(48, 16), dim3(32, 8), 0, stream>>>(w_qkv0, wq0t, 512, 1536);
  wtrans_kernel<<<dim3(48, 16), dim3(32, 8), 0, stream>>>(w_qkv1, wq1t, 512, 1536);
  wtrans_kernel<<<dim3(16, 16), dim3(32, 8), 0, stream>>>(w_proj, wpt, 512, 512);
  wtrans_kernel<<<dim3(64, 16), dim3(32, 8), 0, stream>>>(w_fc1_0, wf10t, 512, 2048);
  wtrans_kernel<<<dim3(16, 64), dim3(32, 8), 0, stream>>>(w_fc2_0, wf20t, 2048, 512);
  wtrans_kernel<<<dim3(64, 16), dim3(32, 8), 0, stream>>>(w_fc1_1, wf11t, 512, 2048);
  wtrans_kernel<<<dim3(16, 64), dim3(32, 8), 0, stream>>>(w_fc2_1, wf21t, 2048, 512);

  // qkv projections
  ln_kernel<<<M, 256, 0, stream>>>(x0, ln00_g, ln00_b, xnb);
  gemm_bf16<0, 0, 0><<<dim3(12, 32), 256, 0, stream>>>((const short*)xnb, (const short*)wq0t,
                                                       b_qkv0, nullptr, qkv0, M, 1536, 512);
  ln_kernel<<<M, 256, 0, stream>>>(x1, ln01_g, ln01_b, xnb);
  gemm_bf16<0, 0, 0><<<dim3(12, 32), 256, 0, stream>>>((const short*)xnb, (const short*)wq1t,
                                                       b_qkv1, nullptr, qkv1, M, 1536, 512);

  // attention 0: q0 with k1/v1
  tableprod_kernel<<<M, 256, 0, stream>>>(qkv0, 1536, table_k, lkbuf, 1.0f);
  tableprod_kernel<<<M, 256, 0, stream>>>(qkv1 + 512, 1536, table_q, lqbuf, 0.125f);
  attn_kernel<<<dim3(64, 8, 4), 256, 0, stream>>>(qkv0, qkv1 + 512, qkv1 + 1024, 1536,
                                                  lkbuf, lqbuf, bucket, table_v, obuf);
  gemm_bf16<0, 1, 0><<<dim3(4, 32), 256, 0, stream>>>((const short*)obuf, (const short*)wpt,
                                                      b_proj, x0, dout0, M, 512, 512);

  // attention 1: q1 with k0/v0
  tableprod_kernel<<<M, 256, 0, stream>>>(qkv1, 1536, table_k, lkbuf, 1.0f);
  tableprod_kernel<<<M, 256, 0, stream>>>(qkv0 + 512, 1536, table_q, lqbuf, 0.125f);
  attn_kernel<<<dim3(64, 8, 4), 256, 0, stream>>>(qkv1, qkv0 + 512, qkv0 + 1024, 1536,
                                                  lkbuf, lqbuf, bucket, table_v, obuf);
  gemm_bf16<0, 1, 0><<<dim3(4, 32), 256, 0, stream>>>((const short*)obuf, (const short*)wpt,
                                                      b_proj, x1, dout1, M, 512, 512);

  // MLP 0  (hbufb aliases qkv0: qkv dead after attention phase)
  ln_kernel<<<M, 256, 0, stream>>>(dout0, ln10_g, ln10_b, xnb);
  gemm_bf16<1, 0, 1><<<dim3(16, 32), 256, 0, stream>>>((const short*)xnb, (const short*)wf10t,
                                                       b_fc1_0, nullptr, hbufb, M, 2048, 512);
  gemm_bf16<0, 1, 0><<<dim3(4, 32), 256, 0, stream>>>((const short*)hbufb, (const short*)wf20t,
                                                      b_fc2_0, dout0, dout0, M, 512, 2048);

  // MLP 1
  ln_kernel<<<M, 256, 0, stream>>>(dout1, ln11_g, ln11_b, xnb);
  gemm_bf16<1, 0, 1><<<dim3(16, 32), 256, 0, stream>>>((const short*)xnb, (const short*)wf11t,
                                                       b_fc1_1, nullptr, hbufb, M, 2048, 512);
  gemm_bf16<0, 1, 0><<<dim3(4, 32), 256, 0, stream>>>((const short*)hbufb, (const short*)wf21t,
                                                      b_fc2_1, dout1, dout1, M, 512, 2048);
}

// Round 5
// 864.521 us; speedup vs baseline: 2.5275x; 2.4317x over previous
//
#include <hip/hip_runtime.h>
#include <hip/hip_bf16.h>
#include <math.h>

#define NFULL 1024
#define CDIM  512
#define HD    64
#define NH    8

typedef __attribute__((ext_vector_type(8))) short s16x8;
typedef __attribute__((ext_vector_type(4))) short s16x4;
typedef __attribute__((ext_vector_type(4))) float f32x4;

__device__ __forceinline__ float b2f(unsigned short u) {
  return __uint_as_float((unsigned)u << 16);
}
__device__ __forceinline__ unsigned short f2b(float f) {
  unsigned u = __float_as_uint(f);
  return (unsigned short)((u + 0x7FFFu + ((u >> 16) & 1u)) >> 16);
}

// ---------------- piecewise bucket index ----------------
__device__ __forceinline__ int pwidx(int d) {
  int ad = d < 0 ? -d : d;
  if (ad <= 1) return d;
  float v = 1.9f + logf((float)ad * (1.0f / 1.9f)) * (1.9f / 2.0794415416798357f); // ln(8)
  v = fminf(v, 3.8f);
  int m = (int)rintf(v);
  if (m > 4) m = 4;
  return d > 0 ? m : -m;
}

// ---------------- layernorm -> bf16 ----------------
__global__ __launch_bounds__(256) void ln_kernel(const float* __restrict__ x,
                                                 const float* __restrict__ g,
                                                 const float* __restrict__ be,
                                                 __hip_bfloat16* __restrict__ y) {
  __shared__ float red[8];
  int row = blockIdx.x, tid = threadIdx.x;
  const float* xr = x + (size_t)row * CDIM;
  float v0 = xr[tid], v1 = xr[tid + 256];
  float s = v0 + v1;
#pragma unroll
  for (int off = 32; off; off >>= 1) s += __shfl_xor(s, off);
  int wid = tid >> 6, lane = tid & 63;
  if (!lane) red[wid] = s;
  __syncthreads();
  float mu = (red[0] + red[1] + red[2] + red[3]) * (1.0f / 512.0f);
  float d0 = v0 - mu, d1 = v1 - mu;
  float q = d0 * d0 + d1 * d1;
#pragma unroll
  for (int off = 32; off; off >>= 1) q += __shfl_xor(q, off);
  if (!lane) red[4 + wid] = q;
  __syncthreads();
  float var = (red[4] + red[5] + red[6] + red[7]) * (1.0f / 512.0f);
  float rstd = rsqrtf(var + 1e-5f);
  __hip_bfloat16* yr = y + (size_t)row * CDIM;
  yr[tid]       = __float2bfloat16(d0 * rstd * g[tid]       + be[tid]);
  yr[tid + 256] = __float2bfloat16(d1 * rstd * g[tid + 256] + be[tid + 256]);
}

// ---------------- weight transpose + bf16 cast ----------------
__global__ __launch_bounds__(256) void wtrans_kernel(const float* __restrict__ W,
                                                     __hip_bfloat16* __restrict__ Wt,
                                                     int K, int N) {
  __shared__ float t[32][33];
  int n0 = blockIdx.x * 32, k0 = blockIdx.y * 32;
  int c = threadIdx.x, r0 = threadIdx.y;
#pragma unroll
  for (int rr = 0; rr < 32; rr += 8) t[r0 + rr][c] = W[(size_t)(k0 + r0 + rr) * N + n0 + c];
  __syncthreads();
#pragma unroll
  for (int rr = 0; rr < 32; rr += 8)
    Wt[(size_t)(n0 + r0 + rr) * K + k0 + c] = __float2bfloat16(t[c][r0 + rr]);
}

__device__ __forceinline__ float gelu_f(float x) {
  return 0.5f * x * (1.0f + erff(x * 0.7071067811865475f));
}

// ---------------- bf16 MFMA GEMM (from round 4, verified) ----------------
template <int ACT, int RES, int OUTBF>
__global__ __launch_bounds__(256, 1) void gemm_bf16(const short* __restrict__ A,
                                                    const short* __restrict__ Bt,
                                                    const float* __restrict__ bias,
                                                    const float* __restrict__ res,
                                                    void* __restrict__ Cout,
                                                    int M, int N, int K) {
  __shared__ __attribute__((aligned(16))) short As[128 * 40];
  __shared__ __attribute__((aligned(16))) short Bs[128 * 40];
  const int tid = threadIdx.x;
  const int bm = blockIdx.y * 128, bn = blockIdx.x * 128;
  const int w = tid >> 6, l = tid & 63;
  const int wr = w >> 1, wc = w & 1;
  const int lr = l & 15, lg = l >> 4;
  const int sr = tid >> 1, sh = (tid & 1) * 16;

  f32x4 acc[4][4] = {};

  for (int k0 = 0; k0 < K; k0 += 32) {
    __syncthreads();
    const float4* ga = (const float4*)(A + (size_t)(bm + sr) * K + k0 + sh);
    const float4* gb = (const float4*)(Bt + (size_t)(bn + sr) * K + k0 + sh);
    float4 a0 = ga[0], a1 = ga[1];
    float4 b0 = gb[0], b1 = gb[1];
    *(float4*)&As[sr * 40 + sh]     = a0;
    *(float4*)&As[sr * 40 + sh + 8] = a1;
    *(float4*)&Bs[sr * 40 + sh]     = b0;
    *(float4*)&Bs[sr * 40 + sh + 8] = b1;
    __syncthreads();
    s16x8 af[4], bf[4];
#pragma unroll
    for (int mi = 0; mi < 4; ++mi)
      af[mi] = *(const s16x8*)&As[(wr * 64 + mi * 16 + lr) * 40 + lg * 8];
#pragma unroll
    for (int ni = 0; ni < 4; ++ni)
      bf[ni] = *(const s16x8*)&Bs[(wc * 64 + ni * 16 + lr) * 40 + lg * 8];
#pragma unroll
    for (int mi = 0; mi < 4; ++mi)
#pragma unroll
      for (int ni = 0; ni < 4; ++ni)
        acc[mi][ni] = __builtin_amdgcn_mfma_f32_16x16x32_bf16(af[mi], bf[ni], acc[mi][ni], 0, 0, 0);
  }
  float bv[4];
#pragma unroll
  for (int ni = 0; ni < 4; ++ni) bv[ni] = bias[bn + wc * 64 + ni * 16 + lr];
#pragma unroll
  for (int mi = 0; mi < 4; ++mi) {
#pragma unroll
    for (int j = 0; j < 4; ++j) {
      int row = bm + wr * 64 + mi * 16 + lg * 4 + j;
#pragma unroll
      for (int ni = 0; ni < 4; ++ni) {
        int col = bn + wc * 64 + ni * 16 + lr;
        float vv = acc[mi][ni][j] + bv[ni];
        if (ACT) vv = gelu_f(vv);
        if (RES) vv += res[(size_t)row * N + col];
        if (OUTBF) ((__hip_bfloat16*)Cout)[(size_t)row * N + col] = __float2bfloat16(vv);
        else       ((float*)Cout)[(size_t)row * N + col] = vv;
      }
    }
  }
}

// ---------------- prep: qkvb bf16 [4096][1536] -> Qb/Kb rows + Vt transposed ----------------
// Qb/Kb: [(b*8+h)*1024 + n][64] bf16.  Vtb: [(b*8+h)*64 + d][1024] bf16.
__global__ __launch_bounds__(256) void prep_kernel(const short* __restrict__ qkvb,
                                                   short* __restrict__ Qb,
                                                   short* __restrict__ Kb,
                                                   short* __restrict__ Vtb) {
  __shared__ short vlds[64 * 72];
  const int tid = threadIdx.x;
  const int n0 = blockIdx.x * 64;
  const int b = blockIdx.y;

  // Q/K reorder copy (cols 0..1023)
#pragma unroll 4
  for (int it = 0; it < 32; ++it) {
    int e = tid + it * 256;
    int n = e >> 7, c8 = (e & 127) * 8;
    s16x8 v = *(const s16x8*)(qkvb + ((size_t)(b * NFULL + n0 + n)) * 1536 + c8);
    int hh = c8 >> 6, d8 = c8 & 63;
    if (hh < 8)
      *(s16x8*)(Qb + ((size_t)(b * 8 + hh) * NFULL + n0 + n) * 64 + d8) = v;
    else
      *(s16x8*)(Kb + ((size_t)(b * 8 + hh - 8) * NFULL + n0 + n) * 64 + d8) = v;
  }
  // V transpose per head
  for (int hh = 0; hh < 8; ++hh) {
    __syncthreads();
#pragma unroll
    for (int rep = 0; rep < 2; ++rep) {
      int n = (tid >> 3) + rep * 32, d8 = (tid & 7) * 8;
      *(s16x8*)&vlds[n * 72 + d8] =
          *(const s16x8*)(qkvb + ((size_t)(b * NFULL + n0 + n)) * 1536 + 1024 + hh * 64 + d8);
    }
    __syncthreads();
#pragma unroll
    for (int rep = 0; rep < 2; ++rep) {
      int d = (tid >> 3) + rep * 32, n8 = (tid & 7) * 8;
      s16x8 o;
#pragma unroll
      for (int u = 0; u < 8; ++u) o[u] = vlds[(n8 + u) * 72 + d];
      *(s16x8*)(Vtb + ((size_t)(b * 8 + hh) * 64 + d) * NFULL + n0 + n8) = o;
    }
  }
}

// ---------------- bias GEMM: out[bh, n, c] = scl * dot(X[bh,n,:], T[c,:])  (c<81) ----------------
// X: bf16 rows [(bh)*1024+n][64]. T: fp32 [81][64]. out: bf16 stride-84 rows.
__global__ __launch_bounds__(256) void bias_gemm(const short* __restrict__ Xb,
                                                 const float* __restrict__ Tg,
                                                 short* __restrict__ outg,
                                                 float scl) {
  __shared__ __attribute__((aligned(16))) short tlds[96 * 88];
  const int tid = threadIdx.x;
  const int w = tid >> 6, l = tid & 63;
  const int g = l >> 4, i15 = l & 15;
  const int tile = blockIdx.x, h = blockIdx.y, b = blockIdx.z;
  const size_t bh = (size_t)(b * NH + h);

  for (int f = tid; f < 81 * 16; f += 256) {
    int c = f >> 4, d4 = (f & 15) * 4;
    float4 t4 = *(const float4*)&Tg[c * 64 + d4];
    s16x4 s4 = {(short)f2b(t4.x), (short)f2b(t4.y), (short)f2b(t4.z), (short)f2b(t4.w)};
    *(s16x4*)&tlds[c * 88 + d4] = s4;
  }
  __syncthreads();

  const int r0w = tile * 128 + w * 32;
  s16x8 af[2][2];
#pragma unroll
  for (int nk = 0; nk < 2; ++nk) {
    const short* xr = Xb + (bh * NFULL + r0w + nk * 16 + i15) * 64 + g * 8;
    af[nk][0] = *(const s16x8*)(xr);
    af[nk][1] = *(const s16x8*)(xr + 32);
  }
#pragma unroll
  for (int c0i = 0; c0i < 6; ++c0i) {
    int c0 = c0i * 16;
    s16x8 bf0 = *(const s16x8*)&tlds[(c0 + i15) * 88 + g * 8];
    s16x8 bf1 = *(const s16x8*)&tlds[(c0 + i15) * 88 + 32 + g * 8];
#pragma unroll
    for (int nk = 0; nk < 2; ++nk) {
      f32x4 acc = {0.f, 0.f, 0.f, 0.f};
      acc = __builtin_amdgcn_mfma_f32_16x16x32_bf16(af[nk][0], bf0, acc, 0, 0, 0);
      acc = __builtin_amdgcn_mfma_f32_16x16x32_bf16(af[nk][1], bf1, acc, 0, 0, 0);
      int c = c0 + i15;
      if (c < 81) {
#pragma unroll
        for (int r = 0; r < 4; ++r) {
          int n = r0w + nk * 16 + g * 4 + r;
          outg[(bh * NFULL + n) * 84 + c] = (short)f2b(acc[r] * scl);
        }
      }
    }
  }
}

// ---------------- MFMA attention ----------------
// block = (itile of 64 q-rows, h, b); 4 waves, wave w owns rows i0+16w..+15.
// S^T = K·Q^T (both operands contiguous); P^T via swizzled per-wave LDS;
// O^T = V^T·P^T with V pre-transposed globally. exp without max (scores O(1)).
__global__ __launch_bounds__(256, 3) void attn_mfma(const short* __restrict__ Qb,
                                                    const short* __restrict__ Kb,
                                                    const short* __restrict__ Vtb,
                                                    const short* __restrict__ lkg,
                                                    const short* __restrict__ lqg,
                                                    const float* __restrict__ tv,
                                                    __hip_bfloat16* __restrict__ o) {
  __shared__ __attribute__((aligned(16))) short pbuf[4][1024];  // per-wave P, swizzled
  __shared__ float wbf[64 * 81];                                // histogram
  __shared__ __attribute__((aligned(16))) float tvf[81 * 64];
  __shared__ short pwy9[63], pwx4[63];

  const int tid = threadIdx.x;
  const int w = tid >> 6, l = tid & 63;
  const int g = l >> 4, i15 = l & 15;
  const int i0 = blockIdx.x * 64;
  const int h = blockIdx.y, b = blockIdx.z;
  const size_t bh = (size_t)(b * NH + h);
  const int i = i0 + w * 16 + i15;

  for (int f = tid; f < 1296; f += 256) ((float4*)tvf)[f] = ((const float4*)tv)[f];
  for (int f = tid; f < 5184; f += 256) wbf[f] = 0.f;
  if (tid < 63) {
    int pv = pwidx(tid - 31);
    pwy9[tid] = (short)((pv + 4) * 9);
    pwx4[tid] = (short)(pv + 4);
  }
  __syncthreads();

  const short* qrow = Qb + (bh * NFULL + i) * 64 + g * 8;
  const s16x8 qf0 = *(const s16x8*)(qrow);
  const s16x8 qf1 = *(const s16x8*)(qrow + 32);
  const unsigned short* lkrow = (const unsigned short*)(lkg + (bh * NFULL + i) * 84);
  const unsigned short* lqb = (const unsigned short*)(lqg + bh * NFULL * 84);
  const short* Kbase = Kb + bh * NFULL * 64;
  const short* Vbase = Vtb + bh * 64 * NFULL;
  const int iy = i >> 5, ix = i & 31;
  char* pwc = (char*)&pbuf[w][0];
  const int swz = (i15 & 7) << 4;
  float* wrow = &wbf[(w * 16 + i15) * 81];

  f32x4 oacc[4] = {};
  float psum = 0.f;

  for (int T = 0; T < 16; ++T) {
    const int j0 = T * 64;
    // K fragments (A of S^T) and Vt fragments (A of O^T) — issue loads early
    s16x8 kf[4][2], vf[4][2];
#pragma unroll
    for (int jc = 0; jc < 4; ++jc) {
      const short* kr = Kbase + (size_t)(j0 + jc * 16 + i15) * 64 + g * 8;
      kf[jc][0] = *(const s16x8*)(kr);
      kf[jc][1] = *(const s16x8*)(kr + 32);
    }
#pragma unroll
    for (int nc = 0; nc < 4; ++nc) {
      const short* vr = Vbase + (size_t)(nc * 16 + i15) * NFULL + j0 + g * 8;
      vf[nc][0] = *(const s16x8*)(vr);
      vf[nc][1] = *(const s16x8*)(vr + 32);
    }
    // S^T tiles: D[j_local][i_local]
    f32x4 sacc[4];
    const f32x4 zz = {0.f, 0.f, 0.f, 0.f};
#pragma unroll
    for (int jc = 0; jc < 4; ++jc) {
      sacc[jc] = __builtin_amdgcn_mfma_f32_16x16x32_bf16(kf[jc][0], qf0, zz, 0, 0, 0);
      sacc[jc] = __builtin_amdgcn_mfma_f32_16x16x32_bf16(kf[jc][1], qf1, sacc[jc], 0, 0, 0);
    }
    // bias + exp + histogram + pack P (lane owns row i, j = j0+jc*16+g*4+r)
#pragma unroll
    for (int jc = 0; jc < 4; ++jc) {
      s16x4 pv4;
#pragma unroll
      for (int r = 0; r < 4; ++r) {
        int j = j0 + jc * 16 + g * 4 + r;
        int jy = j >> 5, jx = j & 31;
        int bb = (int)pwy9[iy - jy + 31] + (int)pwx4[ix - jx + 31];
        float sv = sacc[jc][r] * 0.125f + b2f(lkrow[bb]) + b2f(lqb[(size_t)j * 84 + 80 - bb]);
        float p = __expf(sv);
        psum += p;
        atomicAdd(&wrow[bb], p);
        pv4[r] = (short)f2b(p);
      }
      *(s16x4*)(pwc + i15 * 128 + ((jc * 32 + g * 8) ^ swz)) = pv4;
    }
    // P^T fragments (B of O^T) and PV accumulate
    s16x8 pbf0 = *(const s16x8*)(pwc + i15 * 128 + ((16 * g) ^ swz));
    s16x8 pbf1 = *(const s16x8*)(pwc + i15 * 128 + ((64 + 16 * g) ^ swz));
#pragma unroll
    for (int nc = 0; nc < 4; ++nc) {
      oacc[nc] = __builtin_amdgcn_mfma_f32_16x16x32_bf16(vf[nc][0], pbf0, oacc[nc], 0, 0, 0);
      oacc[nc] = __builtin_amdgcn_mfma_f32_16x16x32_bf16(vf[nc][1], pbf1, oacc[nc], 0, 0, 0);
    }
  }

  // row sum (lanes i, i+16, i+32, i+48 hold partials of same row)
  psum += __shfl_xor(psum, 16);
  psum += __shfl_xor(psum, 32);
  const float rn = 1.0f / psum;

  // tv-bucket term: tva[nc][r] = sum_c' wb[i][c'] * tv[c'][nc*16+g*4+r]
  float tva[4][4] = {};
  for (int c1 = 0; c1 < 81; ++c1) {
    float wv = wrow[c1];
#pragma unroll
    for (int nc = 0; nc < 4; ++nc) {
      float4 t4 = *(const float4*)&tvf[c1 * 64 + nc * 16 + g * 4];
      tva[nc][0] = fmaf(wv, t4.x, tva[nc][0]);
      tva[nc][1] = fmaf(wv, t4.y, tva[nc][1]);
      tva[nc][2] = fmaf(wv, t4.z, tva[nc][2]);
      tva[nc][3] = fmaf(wv, t4.w, tva[nc][3]);
    }
  }

  // write O[i][c] bf16 (lane holds c = nc*16 + g*4 + r for its row i)
  short* ob = (short*)o + ((size_t)b * NFULL + i) * CDIM + h * 64;
#pragma unroll
  for (int nc = 0; nc < 4; ++nc) {
    s16x4 o4;
#pragma unroll
    for (int r = 0; r < 4; ++r) o4[r] = (short)f2b((oacc[nc][r] + tva[nc][r]) * rn);
    *(s16x4*)(ob + nc * 16 + g * 4) = o4;
  }
}

// ---------------- launch ----------------
extern "C" void kernel_launch(void* const* d_in, const int* in_sizes, int n_in,
                              void* d_out, int out_size, void* d_ws, size_t ws_size,
                              hipStream_t stream) {
  (void)in_sizes; (void)n_in; (void)out_size; (void)ws_size;
  const float* x0 = (const float*)d_in[0];
  const float* x1 = (const float*)d_in[1];
  const float* ln00_g = (const float*)d_in[2];
  const float* ln00_b = (const float*)d_in[3];
  const float* ln01_g = (const float*)d_in[4];
  const float* ln01_b = (const float*)d_in[5];
  const float* ln10_g = (const float*)d_in[6];
  const float* ln10_b = (const float*)d_in[7];
  const float* ln11_g = (const float*)d_in[8];
  const float* ln11_b = (const float*)d_in[9];
  const float* w_qkv0 = (const float*)d_in[10];
  const float* b_qkv0 = (const float*)d_in[11];
  const float* w_qkv1 = (const float*)d_in[12];
  const float* b_qkv1 = (const float*)d_in[13];
  const float* w_proj = (const float*)d_in[14];
  const float* b_proj = (const float*)d_in[15];
  const float* table_q = (const float*)d_in[16];
  const float* table_k = (const float*)d_in[17];
  const float* table_v = (const float*)d_in[18];
  const float* w_fc1_0 = (const float*)d_in[19];
  const float* b_fc1_0 = (const float*)d_in[20];
  const float* w_fc2_0 = (const float*)d_in[21];
  const float* b_fc2_0 = (const float*)d_in[22];
  const float* w_fc1_1 = (const float*)d_in[23];
  const float* b_fc1_1 = (const float*)d_in[24];
  const float* w_fc2_1 = (const float*)d_in[25];
  const float* b_fc2_1 = (const float*)d_in[26];

  char* base = (char*)d_ws;
  short* qkvb0 = (short*)(base + 0);              // 12.6 MB  (4096x1536 bf16)
  short* qkvb1 = (short*)(base + 12582912);       // 12.6 MB
  short* Qb0   = (short*)(base + 25165824);       // 4 MB each
  short* Kb0   = (short*)(base + 29360128);
  short* Vtb0  = (short*)(base + 33554432);
  short* Qb1   = (short*)(base + 37748736);
  short* Kb1   = (short*)(base + 41943040);
  short* Vtb1  = (short*)(base + 46137344);
  short* lkg   = (short*)(base + 50331648);       // 5.5 MB (stride-84 rows)
  short* lqg   = (short*)(base + 55836672);       // 5.5 MB
  short* obuf  = (short*)(base + 61341696);       // 4 MB
  __hip_bfloat16* xnb = (__hip_bfloat16*)(base + 65536000);  // 4 MB
  __hip_bfloat16* wq0t  = (__hip_bfloat16*)(base + 69730304);
  __hip_bfloat16* wq1t  = (__hip_bfloat16*)(base + 71303168);
  __hip_bfloat16* wpt   = (__hip_bfloat16*)(base + 72876032);
  __hip_bfloat16* wf10t = (__hip_bfloat16*)(base + 73400320);
  __hip_bfloat16* wf20t = (__hip_bfloat16*)(base + 75497472);
  __hip_bfloat16* wf11t = (__hip_bfloat16*)(base + 77594624);
  __hip_bfloat16* wf21t = (__hip_bfloat16*)(base + 79691776); // end ~81.8 MB
  short* hbufb = (short*)(base + 0);              // MLP hidden 16 MB, aliases dead qkvb
  float* dout0 = (float*)d_out;
  float* dout1 = dout0 + (size_t)4 * 1024 * 512;

  const int M = 4096;

  // weight transposes
  wtrans_kernel<<<dim3(48, 16), dim3(32, 8), 0, stream>>>(w_qkv0, wq0t, 512, 1536);
  wtrans_kernel<<<dim3(48, 16), dim3(32, 8), 0, stream>>>(w_qkv1, wq1t, 512, 1536);
  wtrans_kernel<<<dim3(16, 16), dim3(32, 8), 0, stream>>>(w_proj, wpt, 512, 512);
  wtrans_kernel<<<dim3(64, 16), dim3(32, 8), 0, stream>>>(w_fc1_0, wf10t, 512, 2048);
  wtrans_kernel<<<dim3(16, 64), dim3(32, 8), 0, stream>>>(w_fc2_0, wf20t, 2048, 512);
  wtrans_kernel<<<dim3(64, 16), dim3(32, 8), 0, stream>>>(w_fc1_1, wf11t, 512, 2048);
  wtrans_kernel<<<dim3(16, 64), dim3(32, 8), 0, stream>>>(w_fc2_1, wf21t, 2048, 512);

  // qkv projections (bf16 out)
  ln_kernel<<<M, 256, 0, stream>>>(x0, ln00_g, ln00_b, xnb);
  gemm_bf16<0, 0, 1><<<dim3(12, 32), 256, 0, stream>>>((const short*)xnb, (const short*)wq0t,
                                                       b_qkv0, nullptr, qkvb0, M, 1536, 512);
  ln_kernel<<<M, 256, 0, stream>>>(x1, ln01_g, ln01_b, xnb);
  gemm_bf16<0, 0, 1><<<dim3(12, 32), 256, 0, stream>>>((const short*)xnb, (const short*)wq1t,
                                                       b_qkv1, nullptr, qkvb1, M, 1536, 512);

  // head-layout prep (+ V transpose)
  prep_kernel<<<dim3(16, 4), 256, 0, stream>>>(qkvb0, Qb0, Kb0, Vtb0);
  prep_kernel<<<dim3(16, 4), 256, 0, stream>>>(qkvb1, Qb1, Kb1, Vtb1);

  // attention 0: q0 with k1/v1
  bias_gemm<<<dim3(8, 8, 4), 256, 0, stream>>>(Qb0, table_k, lkg, 1.0f);
  bias_gemm<<<dim3(8, 8, 4), 256, 0, stream>>>(Kb1, table_q, lqg, 0.125f);
  attn_mfma<<<dim3(16, 8, 4), 256, 0, stream>>>(Qb0, Kb1, Vtb1, lkg, lqg, table_v,
                                                (__hip_bfloat16*)obuf);
  gemm_bf16<0, 1, 0><<<dim3(4, 32), 256, 0, stream>>>(obuf, (const short*)wpt,
                                                      b_proj, x0, dout0, M, 512, 512);

  // attention 1: q1 with k0/v0
  bias_gemm<<<dim3(8, 8, 4), 256, 0, stream>>>(Qb1, table_k, lkg, 1.0f);
  bias_gemm<<<dim3(8, 8, 4), 256, 0, stream>>>(Kb0, table_q, lqg, 0.125f);
  attn_mfma<<<dim3(16, 8, 4), 256, 0, stream>>>(Qb1, Kb0, Vtb0, lkg, lqg, table_v,
                                                (__hip_bfloat16*)obuf);
  gemm_bf16<0, 1, 0><<<dim3(4, 32), 256, 0, stream>>>(obuf, (const short*)wpt,
                                                      b_proj, x1, dout1, M, 512, 512);

  // MLP 0
  ln_kernel<<<M, 256, 0, stream>>>(dout0, ln10_g, ln10_b, xnb);
  gemm_bf16<1, 0, 1><<<dim3(16, 32), 256, 0, stream>>>((const short*)xnb, (const short*)wf10t,
                                                       b_fc1_0, nullptr, hbufb, M, 2048, 512);
  gemm_bf16<0, 1, 0><<<dim3(4, 32), 256, 0, stream>>>(hbufb, (const short*)wf20t,
                                                      b_fc2_0, dout0, dout0, M, 512, 2048);

  // MLP 1
  ln_kernel<<<M, 256, 0, stream>>>(dout1, ln11_g, ln11_b, xnb);
  gemm_bf16<1, 0, 1><<<dim3(16, 32), 256, 0, stream>>>((const short*)xnb, (const short*)wf11t,
                                                       b_fc1_1, nullptr, hbufb, M, 2048, 512);
  gemm_bf16<0, 1, 0><<<dim3(4, 32), 256, 0, stream>>>(hbufb, (const short*)wf21t,
                                                      b_fc2_1, dout1, dout1, M, 512, 2048);
}